// Round 2
// baseline (725.426 us; speedup 1.0000x reference)
//
#include <hip/hip_runtime.h>
#include <stdint.h>

#define BB 8
#define TT 4096
#define CC 1024
#define HH 16
#define FF 4096
#define KSEL 512

typedef unsigned short u16t;
typedef unsigned int u32t;
typedef unsigned long long u64t;
typedef __attribute__((ext_vector_type(8))) short s16x8;
typedef __attribute__((ext_vector_type(4))) float f32x4;

// ---------------- helpers ----------------
static __device__ __forceinline__ u16t f2bf(float f) {
  union { float f; u32t u; } c; c.f = f;
  u32t u = c.u;
  u += 0x7FFFu + ((u >> 16) & 1u);   // RNE
  return (u16t)(u >> 16);
}

static __device__ __forceinline__ f32x4 mfma16(s16x8 a, s16x8 b, f32x4 c) {
  return __builtin_amdgcn_mfma_f32_16x16x32_bf16(a, b, c, 0, 0, 0);
}

// async global->LDS, 16B per lane. LDS dest must be wave-uniform base;
// casts lowered by clang as addrspacecast (NOT integer truncation).
static __device__ __forceinline__ void gload16(const void* g, void* lds) {
  __builtin_amdgcn_global_load_lds(
      (const __attribute__((address_space(1))) void*)g,
      (__attribute__((address_space(3))) void*)lds,
      16, 0, 0);
}

// ---------------- weight transpose + bf16 cast: dst[N][K] = src[K][N] ----------------
__global__ __launch_bounds__(256) void transpose_cvt_k(const float* __restrict__ src,
                                                       u16t* __restrict__ dst, int R, int Cc) {
  __shared__ float tile[64][65];
  int ntc = Cc >> 6;
  int tr = blockIdx.x / ntc, tc = blockIdx.x % ntc;
  int r0 = tr << 6, c0 = tc << 6;
  int t = threadIdx.x;
#pragma unroll
  for (int i = 0; i < 16; ++i) {
    int idx = t + i * 256;
    int rr = idx >> 6, cc = idx & 63;
    tile[rr][cc] = src[(size_t)(r0 + rr) * Cc + c0 + cc];
  }
  __syncthreads();
#pragma unroll
  for (int i = 0; i < 16; ++i) {
    int idx = t + i * 256;
    int rr = idx >> 6, cc = idx & 63;
    dst[(size_t)(c0 + rr) * R + r0 + cc] = f2bf(tile[cc][rr]);
  }
}

// ---------------- router logits: one wave per token row ----------------
__global__ __launch_bounds__(256) void logits_k(const float* __restrict__ x,
                                                const float* __restrict__ Wr,
                                                float* __restrict__ logit) {
  int wid = blockIdx.x * 4 + (threadIdx.x >> 6);
  int lane = threadIdx.x & 63;
  const float4* xr = (const float4*)(x + (size_t)wid * CC);
  const float4* wr = (const float4*)Wr;
  float s = 0.f;
#pragma unroll
  for (int j = 0; j < 4; ++j) {
    float4 a = xr[j * 64 + lane], b = wr[j * 64 + lane];
    s += a.x * b.x + a.y * b.y + a.z * b.z + a.w * b.w;
  }
#pragma unroll
  for (int d = 32; d; d >>= 1) s += __shfl_down(s, d);
  if (!lane) logit[wid] = s;
}

// ---------------- exact top-k (per batch) via bitonic sort ----------------
__global__ __launch_bounds__(1024) void topk_k(const float* __restrict__ logit,
                                               int* __restrict__ sel, float* __restrict__ wsel) {
  __shared__ u64t key[TT];
  __shared__ u64t key2[KSEL];
  int b = blockIdx.x, t = threadIdx.x;
  for (int i = t; i < TT; i += 1024) {
    float v = logit[(size_t)b * TT + i];
    u32t u = __float_as_uint(v);
    u ^= (u & 0x80000000u) ? 0xFFFFFFFFu : 0x80000000u;   // monotonic ascending key
    u64t kd = ((u64t)u << 32) | (u32t)(~i);               // ties: smaller index wins
    key[i] = ~kd;                                         // ascending sort => value-descending
  }
  __syncthreads();
  for (int kk = 2; kk <= TT; kk <<= 1) {
    for (int j = kk >> 1; j > 0; j >>= 1) {
      for (int i = t; i < TT; i += 1024) {
        int ij = i ^ j;
        if (ij > i) {
          u64t a = key[i], c = key[ij];
          bool up = ((i & kk) == 0);
          if ((a > c) == up) { key[i] = c; key[ij] = a; }
        }
      }
      __syncthreads();
    }
  }
  if (t < KSEL) {
    u64t orig = ~key[t];
    u32t mono = (u32t)(orig >> 32);
    u32t idx = ~((u32t)orig);
    u32t uv = (mono & 0x80000000u) ? (mono ^ 0x80000000u) : ~mono;  // un-mono
    key2[t] = ((u64t)idx << 32) | uv;                               // re-sort by index
  }
  __syncthreads();
  for (int kk = 2; kk <= KSEL; kk <<= 1) {
    for (int j = kk >> 1; j > 0; j >>= 1) {
      if (t < KSEL) {
        int i = t, ij = i ^ j;
        if (ij > i) {
          u64t a = key2[i], c = key2[ij];
          bool up = ((i & kk) == 0);
          if ((a > c) == up) { key2[i] = c; key2[ij] = a; }
        }
      }
      __syncthreads();
    }
  }
  if (t < KSEL) {
    u64t e = key2[t];
    sel[(size_t)b * KSEL + t] = (int)(e >> 32);
    wsel[(size_t)b * KSEL + t] = __uint_as_float((u32t)e);
  }
}

// ---------------- copy x -> out ----------------
__global__ __launch_bounds__(256) void copy_k(const float4* __restrict__ src,
                                              float4* __restrict__ dst, int n) {
  int i = blockIdx.x * 256 + threadIdx.x;
  int stride = gridDim.x * 256;
  for (; i < n; i += stride) dst[i] = src[i];
}

// ---------------- gather(optional) + LayerNorm -> bf16 (and f32 tok copy) ----------------
__global__ __launch_bounds__(256) void rowln_k(const float* __restrict__ src,
                                               const int* __restrict__ sel,
                                               const float* __restrict__ gamma,
                                               float* __restrict__ tok,
                                               u16t* __restrict__ hout) {
  int r = blockIdx.x;
  size_t srow;
  if (sel) {
    int b = r >> 9;
    int t = sel[r];
    srow = ((size_t)b * TT + t) * CC;
  } else {
    srow = (size_t)r * CC;
  }
  int c = threadIdx.x;
  float4 v = ((const float4*)(src + srow))[c];
  float s = v.x + v.y + v.z + v.w;
  float ss = v.x * v.x + v.y * v.y + v.z * v.z + v.w * v.w;
#pragma unroll
  for (int d = 32; d; d >>= 1) { s += __shfl_down(s, d); ss += __shfl_down(ss, d); }
  __shared__ float red[8];
  int wv = c >> 6, lane = c & 63;
  if (!lane) { red[wv] = s; red[4 + wv] = ss; }
  __syncthreads();
  float st = red[0] + red[1] + red[2] + red[3];
  float sst = red[4] + red[5] + red[6] + red[7];
  float mu = st * (1.f / CC);
  float var = sst * (1.f / CC) - mu * mu;
  float rstd = rsqrtf(var + 1e-5f);
  float4 gv = ((const float4*)gamma)[c];
  union { u16t u[4]; uint2 d2; } pk;
  pk.u[0] = f2bf((v.x - mu) * rstd * gv.x);
  pk.u[1] = f2bf((v.y - mu) * rstd * gv.y);
  pk.u[2] = f2bf((v.z - mu) * rstd * gv.z);
  pk.u[3] = f2bf((v.w - mu) * rstd * gv.w);
  ((uint2*)(hout + (size_t)r * CC))[c] = pk.d2;
  if (tok) ((float4*)(tok + (size_t)r * CC))[c] = v;
}

// ---------------- 128x128x32 bf16 MFMA GEMM, A[M][K] x B1t[N][K] (+B3t for DUAL) ----------------
// EPI: 0 = write bf16; 1 = outf = aux + acc; 2 = outf += acc (in place); 3 = bf16 silu(acc1)*acc3
template <int EPI>
__global__ __launch_bounds__(256, 2) void gemm_k(const u16t* __restrict__ A,
                                                 const u16t* __restrict__ B1,
                                                 const u16t* __restrict__ B3,
                                                 const float* __restrict__ aux,
                                                 float* __restrict__ outf,
                                                 u16t* __restrict__ outh,
                                                 int M, int N, int K) {
  constexpr bool DUAL = (EPI == 3);
  __shared__ u16t sA[128 * 32];
  __shared__ u16t sB[128 * 32];
  constexpr int SB3 = DUAL ? 128 * 32 : 8;
  __shared__ u16t sB3[SB3];

  int tid = threadIdx.x;
  int bx = blockIdx.x, by = blockIdx.y;
  int lane = tid & 63, wv = tid >> 6;
  int wrow = (wv >> 1) * 64, wcol = (wv & 1) * 64;
  int l15 = lane & 15, g = lane >> 4;

  int sr = tid >> 2;          // staging row 0..63
  int scol = (tid & 3) * 8;   // staging col (bf16 elems)
  const u16t* gA0 = A + (size_t)(by * 128 + sr) * K + scol;
  const u16t* gA1 = gA0 + (size_t)64 * K;
  const u16t* gB0 = B1 + (size_t)(bx * 128 + sr) * K + scol;
  const u16t* gB1 = gB0 + (size_t)64 * K;
  const u16t* gC0 = nullptr;
  const u16t* gC1 = nullptr;
  if constexpr (DUAL) {
    gC0 = B3 + (size_t)(bx * 128 + sr) * K + scol;
    gC1 = gC0 + (size_t)64 * K;
  }
  u16t* lA0 = &sA[wv * 512];
  u16t* lA1 = &sA[2048 + wv * 512];
  u16t* lB0 = &sB[wv * 512];
  u16t* lB1 = &sB[2048 + wv * 512];

  f32x4 zero = {0.f, 0.f, 0.f, 0.f};
  f32x4 acc[4][4];
  f32x4 acc3[DUAL ? 4 : 1][DUAL ? 4 : 1];
#pragma unroll
  for (int m = 0; m < 4; ++m)
#pragma unroll
    for (int n = 0; n < 4; ++n) acc[m][n] = zero;
  if constexpr (DUAL) {
#pragma unroll
    for (int m = 0; m < 4; ++m)
#pragma unroll
      for (int n = 0; n < 4; ++n) acc3[m][n] = zero;
  }

  for (int k0 = 0; k0 < K; k0 += 32) {
    __syncthreads();
    gload16(gA0 + k0, lA0);
    gload16(gA1 + k0, lA1);
    gload16(gB0 + k0, lB0);
    gload16(gB1 + k0, lB1);
    if constexpr (DUAL) {
      gload16(gC0 + k0, &sB3[wv * 512]);
      gload16(gC1 + k0, &sB3[2048 + wv * 512]);
    }
    __syncthreads();

    s16x8 af[4], bf[4];
#pragma unroll
    for (int m = 0; m < 4; ++m)
      af[m] = *(const s16x8*)&sA[(wrow + m * 16 + l15) * 32 + g * 8];
#pragma unroll
    for (int n = 0; n < 4; ++n)
      bf[n] = *(const s16x8*)&sB[(wcol + n * 16 + l15) * 32 + g * 8];
#pragma unroll
    for (int m = 0; m < 4; ++m)
#pragma unroll
      for (int n = 0; n < 4; ++n) acc[m][n] = mfma16(af[m], bf[n], acc[m][n]);
    if constexpr (DUAL) {
      s16x8 cf[4];
#pragma unroll
      for (int n = 0; n < 4; ++n)
        cf[n] = *(const s16x8*)&sB3[(wcol + n * 16 + l15) * 32 + g * 8];
#pragma unroll
      for (int m = 0; m < 4; ++m)
#pragma unroll
        for (int n = 0; n < 4; ++n) acc3[m][n] = mfma16(af[m], cf[n], acc3[m][n]);
    }
  }

  // epilogue: C/D layout col=lane&15, row=4*(lane>>4)+reg  [m89-verified]
#pragma unroll
  for (int m = 0; m < 4; ++m)
#pragma unroll
    for (int n = 0; n < 4; ++n) {
      int row0 = by * 128 + wrow + m * 16 + 4 * g;
      int col = bx * 128 + wcol + n * 16 + l15;
#pragma unroll
      for (int r = 0; r < 4; ++r) {
        size_t idx = (size_t)(row0 + r) * N + col;
        float v = acc[m][n][r];
        if constexpr (EPI == 0) {
          outh[idx] = f2bf(v);
        } else if constexpr (EPI == 1) {
          outf[idx] = aux[idx] + v;
        } else if constexpr (EPI == 2) {
          outf[idx] += v;
        } else {
          float a3 = acc3[m][n][r];
          float u = v / (1.f + __expf(-v)) * a3;   // silu(g1)*g3
          outh[idx] = f2bf(u);
        }
      }
    }
}

// ---------------- flash attention: block = (b, h, 128 q rows), 4 waves ----------------
__global__ __launch_bounds__(256) void attn_k(const u16t* __restrict__ qkv, u16t* __restrict__ oat) {
  __shared__ u16t sK[64][72];
  __shared__ u16t sVt[64][72];
  __shared__ u16t sP[4][32][72];
  int bid = blockIdx.x;
  int qc = bid & 3, h = (bid >> 2) & 15, b = bid >> 6;
  int q0 = qc * 128;
  int tid = threadIdx.x, lane = tid & 63, wv = tid >> 6;
  int l15 = lane & 15, g = lane >> 4;

  // Q fragments (held whole loop). k-slot mapping (8*g+i) used consistently for A and B.
  s16x8 qf[2][2];
  size_t qbase = (size_t)(b * KSEL + q0 + wv * 32) * (3 * CC);
#pragma unroll
  for (int mq = 0; mq < 2; ++mq)
#pragma unroll
    for (int ks = 0; ks < 2; ++ks)
      qf[mq][ks] = *(const s16x8*)&qkv[qbase + (size_t)(mq * 16 + l15) * (3 * CC) + h * 64 + ks * 32 + g * 8];

  f32x4 zero = {0.f, 0.f, 0.f, 0.f};
  float m_st[2][4], l_st[2][4];
  f32x4 o[2][4];
#pragma unroll
  for (int mq = 0; mq < 2; ++mq) {
#pragma unroll
    for (int r = 0; r < 4; ++r) { m_st[mq][r] = -1e30f; l_st[mq][r] = 0.f; }
#pragma unroll
    for (int d = 0; d < 4; ++d) o[mq][d] = zero;
  }

  int nkt = (q0 + 128) / 64;
  for (int kt = 0; kt < nkt; ++kt) {
    __syncthreads();
    {  // stage K tile [64 keys][64 dh]
      int key = tid >> 2, dh0 = (tid & 3) * 16;
      const u16t* src = &qkv[(size_t)(b * KSEL + kt * 64 + key) * (3 * CC) + CC + h * 64 + dh0];
      s16x8 v0 = *(const s16x8*)src, v1 = *(const s16x8*)(src + 8);
      *(s16x8*)&sK[key][dh0] = v0;
      *(s16x8*)&sK[key][dh0 + 8] = v1;
    }
    {  // stage V transposed [64 dh][64 keys]
      int key = tid >> 2, dh0 = (tid & 3) * 16;
      const u16t* src = &qkv[(size_t)(b * KSEL + kt * 64 + key) * (3 * CC) + 2 * CC + h * 64 + dh0];
      s16x8 v0 = *(const s16x8*)src, v1 = *(const s16x8*)(src + 8);
#pragma unroll
      for (int j = 0; j < 8; ++j) {
        sVt[dh0 + j][key] = (u16t)v0[j];
        sVt[dh0 + 8 + j][key] = (u16t)v1[j];
      }
    }
    __syncthreads();

    // S = Q K^T
    f32x4 s[2][4];
#pragma unroll
    for (int mq = 0; mq < 2; ++mq)
#pragma unroll
      for (int nk = 0; nk < 4; ++nk) s[mq][nk] = zero;
#pragma unroll
    for (int nk = 0; nk < 4; ++nk)
#pragma unroll
      for (int ks = 0; ks < 2; ++ks) {
        s16x8 kf = *(const s16x8*)&sK[nk * 16 + l15][ks * 32 + g * 8];
        s[0][nk] = mfma16(qf[0][ks], kf, s[0][nk]);
        s[1][nk] = mfma16(qf[1][ks], kf, s[1][nk]);
      }
    // scale + causal mask
#pragma unroll
    for (int mq = 0; mq < 2; ++mq)
#pragma unroll
      for (int nk = 0; nk < 4; ++nk)
#pragma unroll
        for (int r = 0; r < 4; ++r) {
          int qrow = q0 + wv * 32 + mq * 16 + 4 * g + r;
          int kcol = kt * 64 + nk * 16 + l15;
          float val = s[mq][nk][r] * 0.125f;
          s[mq][nk][r] = (kcol > qrow) ? -1e30f : val;
        }
    // online softmax
    float sc[2][4];
#pragma unroll
    for (int mq = 0; mq < 2; ++mq)
#pragma unroll
      for (int r = 0; r < 4; ++r) {
        float mx = fmaxf(fmaxf(s[mq][0][r], s[mq][1][r]), fmaxf(s[mq][2][r], s[mq][3][r]));
#pragma unroll
        for (int d = 1; d < 16; d <<= 1) mx = fmaxf(mx, __shfl_xor(mx, d));
        float mnew = fmaxf(m_st[mq][r], mx);
        sc[mq][r] = __expf(m_st[mq][r] - mnew);
        m_st[mq][r] = mnew;
      }
    float lsum[2][4];
#pragma unroll
    for (int mq = 0; mq < 2; ++mq)
#pragma unroll
      for (int r = 0; r < 4; ++r) lsum[mq][r] = 0.f;
#pragma unroll
    for (int mq = 0; mq < 2; ++mq)
#pragma unroll
      for (int nk = 0; nk < 4; ++nk)
#pragma unroll
        for (int r = 0; r < 4; ++r) {
          float p = __expf(s[mq][nk][r] - m_st[mq][r]);
          lsum[mq][r] += p;
          sP[wv][mq * 16 + 4 * g + r][nk * 16 + l15] = f2bf(p);
        }
#pragma unroll
    for (int mq = 0; mq < 2; ++mq)
#pragma unroll
      for (int r = 0; r < 4; ++r) {
        float ls = lsum[mq][r];
#pragma unroll
        for (int d = 1; d < 16; d <<= 1) ls += __shfl_xor(ls, d);
        l_st[mq][r] = l_st[mq][r] * sc[mq][r] + ls;
      }
#pragma unroll
    for (int mq = 0; mq < 2; ++mq)
#pragma unroll
      for (int dhf = 0; dhf < 4; ++dhf)
#pragma unroll
        for (int r = 0; r < 4; ++r) o[mq][dhf][r] *= sc[mq][r];
    // O += P V  (same-wave LDS write->read; compiler inserts lgkmcnt)
    s16x8 pa[2][2];
#pragma unroll
    for (int mq = 0; mq < 2; ++mq)
#pragma unroll
      for (int ks = 0; ks < 2; ++ks)
        pa[mq][ks] = *(const s16x8*)&sP[wv][mq * 16 + l15][ks * 32 + g * 8];
#pragma unroll
    for (int dhf = 0; dhf < 4; ++dhf)
#pragma unroll
      for (int ks = 0; ks < 2; ++ks) {
        s16x8 vb = *(const s16x8*)&sVt[dhf * 16 + l15][ks * 32 + g * 8];
        o[0][dhf] = mfma16(pa[0][ks], vb, o[0][dhf]);
        o[1][dhf] = mfma16(pa[1][ks], vb, o[1][dhf]);
      }
  }
  // epilogue
#pragma unroll
  for (int mq = 0; mq < 2; ++mq)
#pragma unroll
    for (int dhf = 0; dhf < 4; ++dhf)
#pragma unroll
      for (int r = 0; r < 4; ++r) {
        float v = o[mq][dhf][r] / l_st[mq][r];
        size_t row = (size_t)(b * KSEL + q0 + wv * 32 + mq * 16 + 4 * g + r);
        oat[row * CC + h * 64 + dhf * 16 + l15] = f2bf(v);
      }
}

// ---------------- scatter: out[b, sel, :] += y * w ----------------
__global__ __launch_bounds__(256) void scatter_k(const float* __restrict__ y,
                                                 const int* __restrict__ sel,
                                                 const float* __restrict__ wsel,
                                                 float* __restrict__ out) {
  int r = blockIdx.x;
  int b = r >> 9;
  int t = sel[r];
  float wgt = wsel[r];
  float4* orow = (float4*)(out + ((size_t)b * TT + t) * CC);
  const float4* yrow = (const float4*)(y + (size_t)r * CC);
  int c = threadIdx.x;
  float4 ov = orow[c], v = yrow[c];
  ov.x += v.x * wgt; ov.y += v.y * wgt; ov.z += v.z * wgt; ov.w += v.w * wgt;
  orow[c] = ov;
}

// ---------------- launch ----------------
extern "C" void kernel_launch(void* const* d_in, const int* in_sizes, int n_in,
                              void* d_out, int out_size, void* d_ws, size_t ws_size,
                              hipStream_t stream) {
  (void)in_sizes; (void)n_in; (void)out_size; (void)ws_size;
  const float* x     = (const float*)d_in[0];
  const float* Wr    = (const float*)d_in[2];
  const float* ln1_g = (const float*)d_in[3];
  const float* Wqkv  = (const float*)d_in[4];
  const float* Wo    = (const float*)d_in[5];
  const float* ln2_g = (const float*)d_in[6];
  const float* W1    = (const float*)d_in[7];
  const float* W3    = (const float*)d_in[8];
  const float* W2    = (const float*)d_in[9];
  float* out = (float*)d_out;
  char* ws = (char*)d_ws;

  // ws layout (bytes); buffers reused when dataflow-dead
  u16t* Wqkv_t = (u16t*)(ws + 0);          //  6291456
  u16t* Wo_t   = (u16t*)(ws + 6291456);    //  2097152
  u16t* W1_t   = (u16t*)(ws + 8388608);    //  8388608
  u16t* W3_t   = (u16t*)(ws + 16777216);   //  8388608
  u16t* W2_t   = (u16t*)(ws + 25165824);   //  8388608
  float* logit = (float*)(ws + 33554432);  //   131072
  int*   sel   = (int*)(ws + 33685504);    //    16384
  float* wsel  = (float*)(ws + 33701888);  //    16384
  float* tok   = (float*)(ws + 33718272);  // 16777216
  u16t* hbuf   = (u16t*)(ws + 50495488);   //  8388608 (reused as mbuf)
  u16t* qkv    = (u16t*)(ws + 58884096);   // 25165824 (qkv+oat reused as ubuf)
  u16t* oat    = (u16t*)(ws + 84049920);   //  8388608
  float* ybuf  = (float*)(ws + 92438528);  // 16777216
  u16t* mbuf   = hbuf;
  u16t* ubuf   = qkv;                      // 33554432 spans qkv+oat

  transpose_cvt_k<<<dim3(16 * 48), 256, 0, stream>>>(Wqkv, Wqkv_t, 1024, 3072);
  transpose_cvt_k<<<dim3(16 * 16), 256, 0, stream>>>(Wo, Wo_t, 1024, 1024);
  transpose_cvt_k<<<dim3(16 * 64), 256, 0, stream>>>(W1, W1_t, 1024, 4096);
  transpose_cvt_k<<<dim3(16 * 64), 256, 0, stream>>>(W3, W3_t, 1024, 4096);
  transpose_cvt_k<<<dim3(64 * 16), 256, 0, stream>>>(W2, W2_t, 4096, 1024);

  logits_k<<<dim3(BB * TT / 4), 256, 0, stream>>>(x, Wr, logit);
  topk_k<<<dim3(BB), 1024, 0, stream>>>(logit, sel, wsel);
  copy_k<<<dim3(2048), 256, 0, stream>>>((const float4*)x, (float4*)out, BB * TT * CC / 4);
  rowln_k<<<dim3(BB * KSEL), 256, 0, stream>>>(x, sel, ln1_g, tok, hbuf);

  gemm_k<0><<<dim3(3072 / 128, 4096 / 128), 256, 0, stream>>>(hbuf, Wqkv_t, nullptr, nullptr, nullptr, qkv, 4096, 3072, 1024);
  attn_k<<<dim3(BB * HH * 4), 256, 0, stream>>>(qkv, oat);
  gemm_k<1><<<dim3(1024 / 128, 4096 / 128), 256, 0, stream>>>(oat, Wo_t, nullptr, tok, ybuf, nullptr, 4096, 1024, 1024);
  rowln_k<<<dim3(BB * KSEL), 256, 0, stream>>>(ybuf, nullptr, ln2_g, nullptr, mbuf);
  gemm_k<3><<<dim3(4096 / 128, 4096 / 128), 256, 0, stream>>>(mbuf, W1_t, W3_t, nullptr, nullptr, ubuf, 4096, 4096, 1024);
  gemm_k<2><<<dim3(1024 / 128, 4096 / 128), 256, 0, stream>>>(ubuf, W2_t, nullptr, nullptr, ybuf, nullptr, 4096, 1024, 4096);
  scatter_k<<<dim3(BB * KSEL), 256, 0, stream>>>(ybuf, sel, wsel, out);
}

// Round 6
// 671.033 us; speedup vs baseline: 1.0811x; 1.0811x over previous
//
#include <hip/hip_runtime.h>
#include <stdint.h>

#define BB 8
#define TT 4096
#define CC 1024
#define HH 16
#define FF 4096
#define KSEL 512

typedef unsigned short u16t;
typedef unsigned int u32t;
typedef unsigned long long u64t;
typedef __attribute__((ext_vector_type(8))) short s16x8;
typedef __attribute__((ext_vector_type(4))) float f32x4;

// ---------------- helpers ----------------
static __device__ __forceinline__ u16t f2bf(float f) {
  union { float f; u32t u; } c; c.f = f;
  u32t u = c.u;
  u += 0x7FFFu + ((u >> 16) & 1u);   // RNE
  return (u16t)(u >> 16);
}

static __device__ __forceinline__ f32x4 mfma16(s16x8 a, s16x8 b, f32x4 c) {
  return __builtin_amdgcn_mfma_f32_16x16x32_bf16(a, b, c, 0, 0, 0);
}

// async global->LDS, 16B per lane. LDS dest must be wave-uniform base.
static __device__ __forceinline__ void gload16(const void* g, void* lds) {
  __builtin_amdgcn_global_load_lds(
      (const __attribute__((address_space(1))) void*)g,
      (__attribute__((address_space(3))) void*)lds,
      16, 0, 0);
}

// ---------------- weight transpose + bf16 cast: dst[N][K] = src[K][N] ----------------
__global__ __launch_bounds__(256) void transpose_cvt_k(const float* __restrict__ src,
                                                       u16t* __restrict__ dst, int R, int Cc) {
  __shared__ float tile[64][65];
  int ntc = Cc >> 6;
  int tr = blockIdx.x / ntc, tc = blockIdx.x % ntc;
  int r0 = tr << 6, c0 = tc << 6;
  int t = threadIdx.x;
#pragma unroll
  for (int i = 0; i < 16; ++i) {
    int idx = t + i * 256;
    int rr = idx >> 6, cc = idx & 63;
    tile[rr][cc] = src[(size_t)(r0 + rr) * Cc + c0 + cc];
  }
  __syncthreads();
#pragma unroll
  for (int i = 0; i < 16; ++i) {
    int idx = t + i * 256;
    int rr = idx >> 6, cc = idx & 63;
    dst[(size_t)(c0 + rr) * R + r0 + cc] = f2bf(tile[cc][rr]);
  }
}

// ---------------- router logits: one wave per token row ----------------
__global__ __launch_bounds__(256) void logits_k(const float* __restrict__ x,
                                                const float* __restrict__ Wr,
                                                float* __restrict__ logit) {
  int wid = blockIdx.x * 4 + (threadIdx.x >> 6);
  int lane = threadIdx.x & 63;
  const float4* xr = (const float4*)(x + (size_t)wid * CC);
  const float4* wr = (const float4*)Wr;
  float s = 0.f;
#pragma unroll
  for (int j = 0; j < 4; ++j) {
    float4 a = xr[j * 64 + lane], b = wr[j * 64 + lane];
    s += a.x * b.x + a.y * b.y + a.z * b.z + a.w * b.w;
  }
#pragma unroll
  for (int d = 32; d; d >>= 1) s += __shfl_down(s, d);
  if (!lane) logit[wid] = s;
}

// ---------------- exact top-k (per batch) via bitonic sort ----------------
__global__ __launch_bounds__(1024) void topk_k(const float* __restrict__ logit,
                                               int* __restrict__ sel, float* __restrict__ wsel) {
  __shared__ u64t key[TT];
  __shared__ u64t key2[KSEL];
  int b = blockIdx.x, t = threadIdx.x;
  for (int i = t; i < TT; i += 1024) {
    float v = logit[(size_t)b * TT + i];
    u32t u = __float_as_uint(v);
    u ^= (u & 0x80000000u) ? 0xFFFFFFFFu : 0x80000000u;   // monotonic ascending key
    u64t kd = ((u64t)u << 32) | (u32t)(~i);               // ties: smaller index wins
    key[i] = ~kd;                                         // ascending sort => value-descending
  }
  __syncthreads();
  for (int kk = 2; kk <= TT; kk <<= 1) {
    for (int j = kk >> 1; j > 0; j >>= 1) {
      for (int i = t; i < TT; i += 1024) {
        int ij = i ^ j;
        if (ij > i) {
          u64t a = key[i], c = key[ij];
          bool up = ((i & kk) == 0);
          if ((a > c) == up) { key[i] = c; key[ij] = a; }
        }
      }
      __syncthreads();
    }
  }
  if (t < KSEL) {
    u64t orig = ~key[t];
    u32t mono = (u32t)(orig >> 32);
    u32t idx = ~((u32t)orig);
    u32t uv = (mono & 0x80000000u) ? (mono ^ 0x80000000u) : ~mono;  // un-mono
    key2[t] = ((u64t)idx << 32) | uv;                               // re-sort by index
  }
  __syncthreads();
  for (int kk = 2; kk <= KSEL; kk <<= 1) {
    for (int j = kk >> 1; j > 0; j >>= 1) {
      if (t < KSEL) {
        int i = t, ij = i ^ j;
        if (ij > i) {
          u64t a = key2[i], c = key2[ij];
          bool up = ((i & kk) == 0);
          if ((a > c) == up) { key2[i] = c; key2[ij] = a; }
        }
      }
      __syncthreads();
    }
  }
  if (t < KSEL) {
    u64t e = key2[t];
    sel[(size_t)b * KSEL + t] = (int)(e >> 32);
    wsel[(size_t)b * KSEL + t] = __uint_as_float((u32t)e);
  }
}

// ---------------- copy ----------------
__global__ __launch_bounds__(256) void copy_k(const float4* __restrict__ src,
                                              float4* __restrict__ dst, int n) {
  int i = blockIdx.x * 256 + threadIdx.x;
  int stride = gridDim.x * 256;
  for (; i < n; i += stride) dst[i] = src[i];
}

// ---------------- gather(optional) + LayerNorm -> bf16 (and f32 row copy) ----------------
__global__ __launch_bounds__(256) void rowln_k(const float* __restrict__ src,
                                               const int* __restrict__ sel,
                                               const float* __restrict__ gamma,
                                               float* __restrict__ rowcpy,
                                               u16t* __restrict__ hout) {
  int r = blockIdx.x;
  size_t srow;
  if (sel) {
    int b = r >> 9;
    int t = sel[r];
    srow = ((size_t)b * TT + t) * CC;
  } else {
    srow = (size_t)r * CC;
  }
  int c = threadIdx.x;
  float4 v = ((const float4*)(src + srow))[c];
  float s = v.x + v.y + v.z + v.w;
  float ss = v.x * v.x + v.y * v.y + v.z * v.z + v.w * v.w;
#pragma unroll
  for (int d = 32; d; d >>= 1) { s += __shfl_down(s, d); ss += __shfl_down(ss, d); }
  __shared__ float red[8];
  int wv = c >> 6, lane = c & 63;
  if (!lane) { red[wv] = s; red[4 + wv] = ss; }
  __syncthreads();
  float st = red[0] + red[1] + red[2] + red[3];
  float sst = red[4] + red[5] + red[6] + red[7];
  float mu = st * (1.f / CC);
  float var = sst * (1.f / CC) - mu * mu;
  float rstd = rsqrtf(var + 1e-5f);
  float4 gv = ((const float4*)gamma)[c];
  union { u16t u[4]; uint2 d2; } pk;
  pk.u[0] = f2bf((v.x - mu) * rstd * gv.x);
  pk.u[1] = f2bf((v.y - mu) * rstd * gv.y);
  pk.u[2] = f2bf((v.z - mu) * rstd * gv.z);
  pk.u[3] = f2bf((v.w - mu) * rstd * gv.w);
  ((uint2*)(hout + (size_t)r * CC))[c] = pk.d2;
  if (rowcpy) ((float4*)(rowcpy + (size_t)r * CC))[c] = v;
}

// ---------------- 128x128x64 bf16 MFMA GEMM, swizzled LDS, optional split-K ----------------
// A[M][K] x B1t[N][K] (+B3t for DUAL).
// EPI: 0 = write bf16; 3 = bf16 silu(acc1)*acc3; 4 = atomicAdd f32
// LDS layout: [128 rows][64 k] bf16, 128B rows; slot(row, s) holds logical chunk
// c = s ^ (row&7) (T2 swizzle via pre-swizzled global source; rule #21).
template <int EPI>
__global__ __launch_bounds__(256, 2) void gemm_k(const u16t* __restrict__ A,
                                                 const u16t* __restrict__ B1,
                                                 const u16t* __restrict__ B3,
                                                 float* __restrict__ outf,
                                                 u16t* __restrict__ outh,
                                                 int M, int N, int K, int Kc) {
  constexpr bool DUAL = (EPI == 3);
  __shared__ u16t sA[128 * 64];
  __shared__ u16t sB[128 * 64];
  __shared__ u16t sB3[DUAL ? 128 * 64 : 8];

  int tid = threadIdx.x;
  int bx = blockIdx.x, by = blockIdx.y, kz = blockIdx.z;
  int lane = tid & 63, wv = tid >> 6;
  int wrow = (wv >> 1) * 64, wcol = (wv & 1) * 64;
  int l15 = lane & 15, g = lane >> 4;

  // staging: round j covers rows j*32..j*32+31; lane -> (row, source chunk)
  int srow = wv * 8 + (lane >> 3);
  int cswz = (lane & 7) ^ (lane >> 3);      // pre-swizzled source chunk (involution)
  const u16t* gA = A + (size_t)(by * 128 + srow) * K + cswz * 8;
  const u16t* gB = B1 + (size_t)(bx * 128 + srow) * K + cswz * 8;
  const u16t* gC = nullptr;
  if constexpr (DUAL) gC = B3 + (size_t)(bx * 128 + srow) * K + cswz * 8;

  // read-side swizzled chunks (lane-constant): s = (4*ks + g) ^ (l15&7)
  int s0 = (g ^ (l15 & 7)) * 8;
  int s1 = ((4 | g) ^ (l15 & 7)) * 8;

  f32x4 zero = {0.f, 0.f, 0.f, 0.f};
  f32x4 acc[4][4];
  f32x4 acc3[DUAL ? 4 : 1][DUAL ? 4 : 1];
#pragma unroll
  for (int m = 0; m < 4; ++m)
#pragma unroll
    for (int n = 0; n < 4; ++n) acc[m][n] = zero;
  if constexpr (DUAL) {
#pragma unroll
    for (int m = 0; m < 4; ++m)
#pragma unroll
      for (int n = 0; n < 4; ++n) acc3[m][n] = zero;
  }

  int k0 = kz * Kc, kend = k0 + Kc;
  for (; k0 < kend; k0 += 64) {
    __syncthreads();
#pragma unroll
    for (int j = 0; j < 4; ++j) {
      gload16(gA + (size_t)j * 32 * K + k0, &sA[j * 2048 + wv * 512]);
      gload16(gB + (size_t)j * 32 * K + k0, &sB[j * 2048 + wv * 512]);
      if constexpr (DUAL) gload16(gC + (size_t)j * 32 * K + k0, &sB3[j * 2048 + wv * 512]);
    }
    __syncthreads();

#pragma unroll
    for (int ks = 0; ks < 2; ++ks) {
      int sc = ks ? s1 : s0;
      s16x8 af[4], bf[4];
#pragma unroll
      for (int m = 0; m < 4; ++m)
        af[m] = *(const s16x8*)&sA[(wrow + m * 16 + l15) * 64 + sc];
#pragma unroll
      for (int n = 0; n < 4; ++n)
        bf[n] = *(const s16x8*)&sB[(wcol + n * 16 + l15) * 64 + sc];
#pragma unroll
      for (int m = 0; m < 4; ++m)
#pragma unroll
        for (int n = 0; n < 4; ++n) acc[m][n] = mfma16(af[m], bf[n], acc[m][n]);
      if constexpr (DUAL) {
        s16x8 cf[4];
#pragma unroll
        for (int n = 0; n < 4; ++n)
          cf[n] = *(const s16x8*)&sB3[(wcol + n * 16 + l15) * 64 + sc];
#pragma unroll
        for (int m = 0; m < 4; ++m)
#pragma unroll
          for (int n = 0; n < 4; ++n) acc3[m][n] = mfma16(af[m], cf[n], acc3[m][n]);
      }
    }
  }

  // epilogue: C/D layout col=lane&15, row=4*(lane>>4)+reg  [m89-verified]
#pragma unroll
  for (int m = 0; m < 4; ++m)
#pragma unroll
    for (int n = 0; n < 4; ++n) {
      int row0 = by * 128 + wrow + m * 16 + 4 * g;
      int col = bx * 128 + wcol + n * 16 + l15;
#pragma unroll
      for (int r = 0; r < 4; ++r) {
        size_t idx = (size_t)(row0 + r) * N + col;
        float v = acc[m][n][r];
        if constexpr (EPI == 0) {
          outh[idx] = f2bf(v);
        } else if constexpr (EPI == 4) {
          atomicAdd(&outf[idx], v);
        } else {
          float a3 = acc3[m][n][r];
          float u = v / (1.f + __expf(-v)) * a3;   // silu(g1)*g3
          outh[idx] = f2bf(u);
        }
      }
    }
}

// ---------------- flash attention: block = (b, h, 128 q rows), 4 waves ----------------
__global__ __launch_bounds__(256) void attn_k(const u16t* __restrict__ qkv, u16t* __restrict__ oat) {
  __shared__ u16t sK[64][72];
  __shared__ u16t sVt[64][72];
  __shared__ u16t sP[4][32][72];
  int bid = blockIdx.x;
  int qc = bid & 3, h = (bid >> 2) & 15, b = bid >> 6;
  int q0 = qc * 128;
  int tid = threadIdx.x, lane = tid & 63, wv = tid >> 6;
  int l15 = lane & 15, g = lane >> 4;

  s16x8 qf[2][2];
  size_t qbase = (size_t)(b * KSEL + q0 + wv * 32) * (3 * CC);
#pragma unroll
  for (int mq = 0; mq < 2; ++mq)
#pragma unroll
    for (int ks = 0; ks < 2; ++ks)
      qf[mq][ks] = *(const s16x8*)&qkv[qbase + (size_t)(mq * 16 + l15) * (3 * CC) + h * 64 + ks * 32 + g * 8];

  f32x4 zero = {0.f, 0.f, 0.f, 0.f};
  float m_st[2][4], l_st[2][4];
  f32x4 o[2][4];
#pragma unroll
  for (int mq = 0; mq < 2; ++mq) {
#pragma unroll
    for (int r = 0; r < 4; ++r) { m_st[mq][r] = -1e30f; l_st[mq][r] = 0.f; }
#pragma unroll
    for (int d = 0; d < 4; ++d) o[mq][d] = zero;
  }

  int nkt = (q0 + 128) / 64;
  for (int kt = 0; kt < nkt; ++kt) {
    __syncthreads();
    {  // stage K tile [64 keys][64 dh]
      int key = tid >> 2, dh0 = (tid & 3) * 16;
      const u16t* src = &qkv[(size_t)(b * KSEL + kt * 64 + key) * (3 * CC) + CC + h * 64 + dh0];
      s16x8 v0 = *(const s16x8*)src, v1 = *(const s16x8*)(src + 8);
      *(s16x8*)&sK[key][dh0] = v0;
      *(s16x8*)&sK[key][dh0 + 8] = v1;
    }
    {  // stage V transposed [64 dh][64 keys]
      int key = tid >> 2, dh0 = (tid & 3) * 16;
      const u16t* src = &qkv[(size_t)(b * KSEL + kt * 64 + key) * (3 * CC) + 2 * CC + h * 64 + dh0];
      s16x8 v0 = *(const s16x8*)src, v1 = *(const s16x8*)(src + 8);
#pragma unroll
      for (int j = 0; j < 8; ++j) {
        sVt[dh0 + j][key] = (u16t)v0[j];
        sVt[dh0 + 8 + j][key] = (u16t)v1[j];
      }
    }
    __syncthreads();

    f32x4 s[2][4];
#pragma unroll
    for (int mq = 0; mq < 2; ++mq)
#pragma unroll
      for (int nk = 0; nk < 4; ++nk) s[mq][nk] = zero;
#pragma unroll
    for (int nk = 0; nk < 4; ++nk)
#pragma unroll
      for (int ks = 0; ks < 2; ++ks) {
        s16x8 kf = *(const s16x8*)&sK[nk * 16 + l15][ks * 32 + g * 8];
        s[0][nk] = mfma16(qf[0][ks], kf, s[0][nk]);
        s[1][nk] = mfma16(qf[1][ks], kf, s[1][nk]);
      }
#pragma unroll
    for (int mq = 0; mq < 2; ++mq)
#pragma unroll
      for (int nk = 0; nk < 4; ++nk)
#pragma unroll
        for (int r = 0; r < 4; ++r) {
          int qrow = q0 + wv * 32 + mq * 16 + 4 * g + r;
          int kcol = kt * 64 + nk * 16 + l15;
          float val = s[mq][nk][r] * 0.125f;
          s[mq][nk][r] = (kcol > qrow) ? -1e30f : val;
        }
    float sc[2][4];
#pragma unroll
    for (int mq = 0; mq < 2; ++mq)
#pragma unroll
      for (int r = 0; r < 4; ++r) {
        float mx = fmaxf(fmaxf(s[mq][0][r], s[mq][1][r]), fmaxf(s[mq][2][r], s[mq][3][r]));
#pragma unroll
        for (int d = 1; d < 16; d <<= 1) mx = fmaxf(mx, __shfl_xor(mx, d));
        float mnew = fmaxf(m_st[mq][r], mx);
        sc[mq][r] = __expf(m_st[mq][r] - mnew);
        m_st[mq][r] = mnew;
      }
    float lsum[2][4];
#pragma unroll
    for (int mq = 0; mq < 2; ++mq)
#pragma unroll
      for (int r = 0; r < 4; ++r) lsum[mq][r] = 0.f;
#pragma unroll
    for (int mq = 0; mq < 2; ++mq)
#pragma unroll
      for (int nk = 0; nk < 4; ++nk)
#pragma unroll
        for (int r = 0; r < 4; ++r) {
          float p = __expf(s[mq][nk][r] - m_st[mq][r]);
          lsum[mq][r] += p;
          sP[wv][mq * 16 + 4 * g + r][nk * 16 + l15] = f2bf(p);
        }
#pragma unroll
    for (int mq = 0; mq < 2; ++mq)
#pragma unroll
      for (int r = 0; r < 4; ++r) {
        float ls = lsum[mq][r];
#pragma unroll
        for (int d = 1; d < 16; d <<= 1) ls += __shfl_xor(ls, d);
        l_st[mq][r] = l_st[mq][r] * sc[mq][r] + ls;
      }
#pragma unroll
    for (int mq = 0; mq < 2; ++mq)
#pragma unroll
      for (int dhf = 0; dhf < 4; ++dhf)
#pragma unroll
        for (int r = 0; r < 4; ++r) o[mq][dhf][r] *= sc[mq][r];
    s16x8 pa[2][2];
#pragma unroll
    for (int mq = 0; mq < 2; ++mq)
#pragma unroll
      for (int ks = 0; ks < 2; ++ks)
        pa[mq][ks] = *(const s16x8*)&sP[wv][mq * 16 + l15][ks * 32 + g * 8];
#pragma unroll
    for (int dhf = 0; dhf < 4; ++dhf)
#pragma unroll
      for (int ks = 0; ks < 2; ++ks) {
        s16x8 vb = *(const s16x8*)&sVt[dhf * 16 + l15][ks * 32 + g * 8];
        o[0][dhf] = mfma16(pa[0][ks], vb, o[0][dhf]);
        o[1][dhf] = mfma16(pa[1][ks], vb, o[1][dhf]);
      }
  }
#pragma unroll
  for (int mq = 0; mq < 2; ++mq)
#pragma unroll
    for (int dhf = 0; dhf < 4; ++dhf)
#pragma unroll
      for (int r = 0; r < 4; ++r) {
        float v = o[mq][dhf][r] / l_st[mq][r];
        size_t row = (size_t)(b * KSEL + q0 + wv * 32 + mq * 16 + 4 * g + r);
        oat[row * CC + h * 64 + dhf * 16 + l15] = f2bf(v);
      }
}

// ---------------- scatter: out[b, sel, :] += y * w ----------------
__global__ __launch_bounds__(256) void scatter_k(const float* __restrict__ y,
                                                 const int* __restrict__ sel,
                                                 const float* __restrict__ wsel,
                                                 float* __restrict__ out) {
  int r = blockIdx.x;
  int b = r >> 9;
  int t = sel[r];
  float wgt = wsel[r];
  float4* orow = (float4*)(out + ((size_t)b * TT + t) * CC);
  const float4* yrow = (const float4*)(y + (size_t)r * CC);
  int c = threadIdx.x;
  float4 ov = orow[c], v = yrow[c];
  ov.x += v.x * wgt; ov.y += v.y * wgt; ov.z += v.z * wgt; ov.w += v.w * wgt;
  orow[c] = ov;
}

// ---------------- launch ----------------
extern "C" void kernel_launch(void* const* d_in, const int* in_sizes, int n_in,
                              void* d_out, int out_size, void* d_ws, size_t ws_size,
                              hipStream_t stream) {
  (void)in_sizes; (void)n_in; (void)out_size; (void)ws_size;
  const float* x     = (const float*)d_in[0];
  const float* Wr    = (const float*)d_in[2];
  const float* ln1_g = (const float*)d_in[3];
  const float* Wqkv  = (const float*)d_in[4];
  const float* Wo    = (const float*)d_in[5];
  const float* ln2_g = (const float*)d_in[6];
  const float* W1    = (const float*)d_in[7];
  const float* W3    = (const float*)d_in[8];
  const float* W2    = (const float*)d_in[9];
  float* out = (float*)d_out;
  char* ws = (char*)d_ws;

  u16t* Wqkv_t = (u16t*)(ws + 0);          //  6291456
  u16t* Wo_t   = (u16t*)(ws + 6291456);    //  2097152
  u16t* W1_t   = (u16t*)(ws + 8388608);    //  8388608
  u16t* W3_t   = (u16t*)(ws + 16777216);   //  8388608
  u16t* W2_t   = (u16t*)(ws + 25165824);   //  8388608
  float* logit = (float*)(ws + 33554432);  //   131072
  int*   sel   = (int*)(ws + 33685504);    //    16384
  float* wsel  = (float*)(ws + 33701888);  //    16384
  u16t* hbuf   = (u16t*)(ws + 50495488);   //  8388608 (reused as mbuf)
  u16t* qkv    = (u16t*)(ws + 58884096);   // 25165824 (qkv+oat reused as ubuf)
  u16t* oat    = (u16t*)(ws + 84049920);   //  8388608
  float* ybuf  = (float*)(ws + 92438528);  // 16777216
  u16t* mbuf   = hbuf;
  u16t* ubuf   = qkv;                      // 33554432 spans qkv+oat

  transpose_cvt_k<<<dim3(16 * 48), 256, 0, stream>>>(Wqkv, Wqkv_t, 1024, 3072);
  transpose_cvt_k<<<dim3(16 * 16), 256, 0, stream>>>(Wo, Wo_t, 1024, 1024);
  transpose_cvt_k<<<dim3(16 * 64), 256, 0, stream>>>(W1, W1_t, 1024, 4096);
  transpose_cvt_k<<<dim3(16 * 64), 256, 0, stream>>>(W3, W3_t, 1024, 4096);
  transpose_cvt_k<<<dim3(64 * 16), 256, 0, stream>>>(W2, W2_t, 4096, 1024);

  logits_k<<<dim3(BB * TT / 4), 256, 0, stream>>>(x, Wr, logit);
  topk_k<<<dim3(BB), 1024, 0, stream>>>(logit, sel, wsel);
  copy_k<<<dim3(2048), 256, 0, stream>>>((const float4*)x, (float4*)out, BB * TT * CC / 4);
  // gather + LN1 -> hbuf (bf16); gathered f32 rows -> ybuf (residual base for Wo atomics)
  rowln_k<<<dim3(BB * KSEL), 256, 0, stream>>>(x, sel, ln1_g, ybuf, hbuf);

  // QKV: 4096x3072, K=1024 (grid 768 = 3 blocks/CU)
  gemm_k<0><<<dim3(24, 32), 256, 0, stream>>>(hbuf, Wqkv_t, nullptr, nullptr, qkv, 4096, 3072, 1024, 1024);
  attn_k<<<dim3(BB * HH * 4), 256, 0, stream>>>(qkv, oat);
  // Wo with split-K=2 atomic-add into ybuf (grid 512)
  gemm_k<4><<<dim3(8, 32, 2), 256, 0, stream>>>(oat, Wo_t, nullptr, ybuf, nullptr, 4096, 1024, 1024, 512);
  rowln_k<<<dim3(BB * KSEL), 256, 0, stream>>>(ybuf, nullptr, ln2_g, nullptr, mbuf);
  // W1/W3 dual (grid 1024 = 4 blocks/CU)
  gemm_k<3><<<dim3(32, 32), 256, 0, stream>>>(mbuf, W1_t, W3_t, nullptr, ubuf, 4096, 4096, 1024, 1024);
  // W2 with split-K=4 atomic-add into ybuf (grid 1024 = 4 blocks/CU)
  gemm_k<4><<<dim3(8, 32, 4), 256, 0, stream>>>(ubuf, W2_t, nullptr, ybuf, nullptr, 4096, 1024, 4096, 1024);
  scatter_k<<<dim3(BB * KSEL), 256, 0, stream>>>(ybuf, sel, wsel, out);
}